// Round 1
// baseline (155.220 us; speedup 1.0000x reference)
//
#include <hip/hip_runtime.h>
#include <math.h>

// DigitCaps dynamic routing, MI355X. Round 8: device-side fp16 pre-pack +
// global_load_lds staging.
//
// Round-7 post-mortem: VALUBusy 58% with MfmaUtil 0 and HBM at 10% — VALU/
// latency bound. ~half the issued VALU was overhead: every block re-packed
// W[j] f32->fp16 (54 cvt + 27 ds_write + addr math per thread, duplicated
// 32x per j), the staged ds_write pattern was an 8-way bank conflict
// (SQ_LDS_BANK_CONFLICT 2.29M), and 33 KB LDS capped occupancy at 16
// waves/CU (measured 29%).
//
// Round 8:
//  - prepack_kernel (once per launch, ~30 MB traffic): W -> fp16 uint2 in
//    chunk-major layout Wp[j][c][o][r_local] (c<3: 256 rl; c=3: 128 rl,
//    zero-padded past route 864); u -> fp16 uint2 uP[b][896] (zero-padded).
//    Same cvt_pkrtz rounding as round 7 -> numerics identical.
//  - main kernel stages W via __builtin_amdgcn_global_load_lds width=16:
//    zero staging VALU, no ds_write, linear LDS dest -> no bank conflicts.
//    LDS = 2 x 16,384 = 32,768 B exactly (no pad needed).
//  - 512-thread blocks (8 waves = 8 batches per block): halves per-j W
//    re-fetch, grid 166*16 = 2656; VGPR ~80 -> 24 waves/CU cap.
//  - XCD-bijective swizzle (2656 = 8*332): 16 same-j blocks land on one
//    XCD's L2 consecutively -> Wp[j] (56 KB) stays L2-hot.
//  - zero-padding kills all r<RR guards in u_hat compute; only the exp
//    mask (k==13, lane>=32) survives in the routing iterations.

#define BB 128
#define JJ 166
#define RR 864
#define OO 8
#define KMAX 14            // 14 k-slots of 64 routes; k=13 rl in [64,128), valid lanes<32
#define WP_U2 (JJ * 7168)  // W fp16: per j: 3*2048 + 1024 = 7168 uint2 (57,344 B)
#define UP_U2 (BB * 896)   // u fp16: [b][896] uint2, routes >=864 zeroed

typedef __fp16 h2v __attribute__((ext_vector_type(2)));

__device__ __forceinline__ uint32_t pack2(float a, float b) {
    return __builtin_bit_cast(uint32_t, __builtin_amdgcn_cvt_pkrtz(a, b));
}
__device__ __forceinline__ h2v bc_h2(uint32_t u) {
    return __builtin_bit_cast(h2v, u);
}
__device__ __forceinline__ float lo_f(uint32_t u) {
    return (float)__builtin_bit_cast(h2v, u).x;
}
__device__ __forceinline__ float hi_f(uint32_t u) {
    return (float)__builtin_bit_cast(h2v, u).y;
}

__device__ __forceinline__ float wave_sum(float v) {
#pragma unroll
    for (int m = 32; m >= 1; m >>= 1) v += __shfl_xor(v, m, 64);
    return v;
}

// ---- pre-pass: W f32 [J][R][O][4] -> Wp fp16 chunk-major; u -> uP fp16 ----
__global__ __launch_bounds__(256) void prepack_kernel(
    const float* __restrict__ u, const float* __restrict__ W,
    uint2* __restrict__ ws) {
    const int t = threadIdx.x;
    const int bid = blockIdx.x;
    if (bid < JJ * 4) {
        const int j = bid >> 2;
        const int c = bid & 3;
        const float4* __restrict__ W4 = (const float4*)W;  // [(j*864+r)*8+o]
        uint2* __restrict__ dst = ws + (size_t)j * 7168 + c * 2048;
        if (c < 3) {
            // 2048 elems = [o=i][rl=t]; reads stride-8 float4 (L1-resident per wave)
#pragma unroll
            for (int i = 0; i < 8; ++i) {
                const int r = c * 256 + t;
                const float4 w = W4[((size_t)j * RR + r) * 8 + i];
                dst[i * 256 + t] = make_uint2(pack2(w.x, w.y), pack2(w.z, w.w));
            }
        } else {
            // 1024 elems = [o][rl], rl in [0,128), routes >= 864 zeroed
#pragma unroll
            for (int i = 0; i < 4; ++i) {
                const int e = i * 256 + t;
                const int o = e >> 7;
                const int rl = e & 127;
                float4 w = make_float4(0.f, 0.f, 0.f, 0.f);
                if (rl < 96) w = W4[((size_t)j * RR + 768 + rl) * 8 + o];
                dst[e] = make_uint2(pack2(w.x, w.y), pack2(w.z, w.w));
            }
        }
    } else {
        // u pack: e in [0, 128*896)
        const int e = (bid - JJ * 4) * 256 + t;
        const int b = e / 896;
        const int r = e - b * 896;
        const float4* __restrict__ u4 = (const float4*)u;
        float4 uu = make_float4(0.f, 0.f, 0.f, 0.f);
        if (r < RR) uu = u4[(size_t)b * RR + r];
        ws[WP_U2 + e] = make_uint2(pack2(uu.x, uu.y), pack2(uu.z, uu.w));
    }
}

__global__ __launch_bounds__(512) void digitcaps_kernel(
    const uint2* __restrict__ Wp, const uint2* __restrict__ uP,
    float* __restrict__ out) {
    const int tid = threadIdx.x;
    const int lane = tid & 63;
    const int wave = tid >> 6;

    // XCD-bijective swizzle: 2656 blocks = 8 XCDs x 332. Same-j blocks (16)
    // become consecutive on one XCD -> Wp[j] L2-hot.
    int bid = blockIdx.x;
    bid = (bid & 7) * 332 + (bid >> 3);
    const int j = bid >> 4;
    const int b = ((bid & 15) << 3) + wave;

    // two buffers, each [o][rl] uint2, linear (global_load_lds order). 32,768 B.
    __shared__ uint2 wlds[2][2048];

    const uint2* __restrict__ uPb = uP + (size_t)b * 896;

    uint32_t uh[KMAX][4];  // u_hat packed fp16 pairs; constant-indexed only

    // ---- stage chunk CC into LDS buffer BUF via async global->LDS, 16 B/lane ----
#define STAGE(CC, BUF, ROUNDS)                                                 \
    {                                                                          \
        const char* gsrc =                                                     \
            (const char*)(Wp + (size_t)j * 7168 + (CC) * 2048);                \
        _Pragma("unroll")                                                      \
        for (int i = 0; i < (ROUNDS); ++i) {                                   \
            __builtin_amdgcn_global_load_lds(                                  \
                (const __attribute__((address_space(1))) uint32_t*)            \
                    (gsrc + i * 8192 + tid * 16),                              \
                (__attribute__((address_space(3))) uint32_t*)                  \
                    ((char*)(&wlds[BUF][0]) + i * 8192 + (wave << 10)),        \
                16, 0, 0);                                                     \
        }                                                                      \
    }

    // ---- u_hat for chunk CC (KK k-slots, LDS row stride STRIDE) ----
    // No route guard: W and u are zero-padded past route 864 -> uh = 0 there.
#define COMPUTE(CC, BUF, KK, STRIDE)                                           \
    {                                                                          \
        _Pragma("unroll")                                                      \
        for (int kl = 0; kl < (KK); ++kl) {                                    \
            const int rl = (kl << 6) + lane;                                   \
            const uint2 up = uPb[(CC) * 256 + rl];                             \
            float d[OO];                                                       \
            _Pragma("unroll")                                                  \
            for (int o = 0; o < OO; ++o) {                                     \
                const uint2 ww = wlds[BUF][o * (STRIDE) + rl];                 \
                float t = __builtin_amdgcn_fdot2(bc_h2(ww.x), bc_h2(up.x),     \
                                                 0.0f, false);                 \
                d[o] = __builtin_amdgcn_fdot2(bc_h2(ww.y), bc_h2(up.y), t,     \
                                              false);                          \
            }                                                                  \
            _Pragma("unroll")                                                  \
            for (int o2 = 0; o2 < 4; ++o2)                                     \
                uh[(CC) * 4 + kl][o2] = pack2(d[2 * o2], d[2 * o2 + 1]);       \
        }                                                                      \
    }

    // chunks 0-2: 16,384 B (2 rounds); chunk 3: 8,192 B (1 round, stride 128)
    STAGE(0, 0, 2)
    __syncthreads();
    STAGE(1, 1, 2)        // loads fly while computing chunk 0
    COMPUTE(0, 0, 4, 256)
    __syncthreads();
    STAGE(2, 0, 2)
    COMPUTE(1, 1, 4, 256)
    __syncthreads();
    STAGE(3, 1, 1)
    COMPUTE(2, 0, 4, 256)
    __syncthreads();
    COMPUTE(3, 1, 2, 128)
#undef STAGE
#undef COMPUTE

    float V[OO];  // running sum of past v's (b_r = <uhat_r, V>)
    float v[OO];

    // ---- iteration 0: b=0 -> c uniform = 1/R (packed fp16 partial sums) ----
    {
        h2v accp[4];
#pragma unroll
        for (int o2 = 0; o2 < 4; ++o2) accp[o2] = bc_h2(uh[0][o2]);
#pragma unroll
        for (int k = 1; k < KMAX; ++k)
#pragma unroll
            for (int o2 = 0; o2 < 4; ++o2) accp[o2] += bc_h2(uh[k][o2]);

        float s[OO];
#pragma unroll
        for (int o2 = 0; o2 < 4; ++o2) {
            s[2 * o2]     = wave_sum((float)accp[o2].x) * (1.0f / (float)RR);
            s[2 * o2 + 1] = wave_sum((float)accp[o2].y) * (1.0f / (float)RR);
        }
        float n2 = 0.0f;
#pragma unroll
        for (int o = 0; o < OO; ++o) n2 += s[o] * s[o];
        const float scale = sqrtf(n2) / (1.0f + n2);
#pragma unroll
        for (int o = 0; o < OO; ++o) { v[o] = s[o] * scale; V[o] = v[o]; }
    }

    // ---- iterations 1 and 2 ----
#pragma unroll
    for (int it = 1; it < 3; ++it) {
        // pack V once per iteration for dot2 logits
        uint32_t Vp[4];
#pragma unroll
        for (int o2 = 0; o2 < 4; ++o2)
            Vp[o2] = pack2(V[2 * o2], V[2 * o2 + 1]);

        float zp = 0.0f;
        float sp[OO];
#pragma unroll
        for (int o = 0; o < OO; ++o) sp[o] = 0.0f;

#pragma unroll
        for (int k = 0; k < KMAX; ++k) {
            float br = 0.0f;
#pragma unroll
            for (int o2 = 0; o2 < 4; ++o2)
                br = __builtin_amdgcn_fdot2(bc_h2(uh[k][o2]), bc_h2(Vp[o2]),
                                            br, false);
            // mask invalid routes (k==13, lane>=32): exp(0)=1 would pollute Z
            const float e = (k < KMAX - 1 || lane < 32) ? __expf(br) : 0.0f;
            zp += e;
#pragma unroll
            for (int o2 = 0; o2 < 4; ++o2) {
                sp[2 * o2]     = fmaf(e, lo_f(uh[k][o2]), sp[2 * o2]);
                sp[2 * o2 + 1] = fmaf(e, hi_f(uh[k][o2]), sp[2 * o2 + 1]);
            }
        }
        const float invZ = 1.0f / wave_sum(zp);

        float s[OO];
#pragma unroll
        for (int o = 0; o < OO; ++o) s[o] = wave_sum(sp[o]) * invZ;

        float n2 = 0.0f;
#pragma unroll
        for (int o = 0; o < OO; ++o) n2 += s[o] * s[o];
        const float scale = sqrtf(n2) / (1.0f + n2);
#pragma unroll
        for (int o = 0; o < OO; ++o) v[o] = s[o] * scale;

        if (it < 2) {
#pragma unroll
            for (int o = 0; o < OO; ++o) V[o] += v[o];
        }
    }

    // ---- write out[b][j][o]; v replicated across lanes after butterflies ----
    float outv = 0.0f;
#pragma unroll
    for (int o = 0; o < OO; ++o)
        if (lane == o) outv = v[o];
    if (lane < OO) out[(b * JJ + j) * OO + lane] = outv;
}

extern "C" void kernel_launch(void* const* d_in, const int* in_sizes, int n_in,
                              void* d_out, int out_size, void* d_ws, size_t ws_size,
                              hipStream_t stream) {
    const float* u = (const float*)d_in[0];  // [128, 864, 4]
    const float* W = (const float*)d_in[1];  // [1, 166, 864, 8, 4]
    float* out = (float*)d_out;              // [128, 166, 8]
    uint2* ws = (uint2*)d_ws;                // needs (WP_U2 + UP_U2)*8 = ~10.0 MB

    // pre-pass: 664 W-blocks + 448 u-blocks
    prepack_kernel<<<JJ * 4 + (BB * 896) / 256, 256, 0, stream>>>(u, W, ws);

    // main: 166 j * 16 b-groups, 512 threads (8 waves = 8 batches)
    digitcaps_kernel<<<JJ * 16, 512, 0, stream>>>(ws, ws + WP_U2, out);
}